// Round 10
// baseline (581.500 us; speedup 1.0000x reference)
//
#include <hip/hip_runtime.h>
#include <hip/hip_bf16.h>
#include <cstdint>
#include <cstddef>
#include <type_traits>

typedef _Float16 half8 __attribute__((ext_vector_type(8)));
typedef _Float16 half4v __attribute__((ext_vector_type(4)));
typedef float float4v __attribute__((ext_vector_type(4)));

// ---------------- fused prep: zero cnt/flag + weight convert/transpose ----------------

__global__ void k_prep(int* __restrict__ cnt, int* __restrict__ flag,
                       const float* __restrict__ W1, const float* __restrict__ Wg1,
                       const float* __restrict__ Wg2, _Float16* __restrict__ W1t,
                       _Float16* __restrict__ Wg1t, _Float16* __restrict__ Wg2t,
                       int n, int in_dim, int hid) {
  int idx = blockIdx.x * blockDim.x + threadIdx.x;
  if (idx < n) { cnt[idx] = 0; flag[idx] = 0; return; }
  int w = idx - n;
  int n1 = in_dim * hid;
  int n2 = hid * hid;
  if (w < n1) {
    int nn = w / in_dim, k = w - nn * in_dim;
    W1t[w] = (_Float16)W1[(size_t)k * hid + nn];
  } else if (w < n1 + n2) {
    int i2 = w - n1;
    int nn = i2 / hid, k = i2 - nn * hid;
    Wg1t[i2] = (_Float16)Wg1[(size_t)k * hid + nn];
  } else if (w < n1 + 2 * n2) {
    int i2 = w - n1 - n2;
    int nn = i2 / hid, k = i2 - nn * hid;
    Wg2t[i2] = (_Float16)Wg2[(size_t)k * hid + nn];
  }
}

// ---------------- fused count + S1 mark (one E pass) ----------------

__global__ void k_countmark(const int* __restrict__ src, const int* __restrict__ dst,
                            int* __restrict__ cnt, int* __restrict__ flag,
                            int E, int Batch) {
  int e = blockIdx.x * blockDim.x + threadIdx.x;
  if (e < E) {
    int d = dst[e];
    atomicAdd(&cnt[d], 1);
    if (d < Batch) flag[src[e]] = 1;
  }
  if (e < Batch) flag[e] = 1;
}

// ---------------- hierarchical DUAL scan (cnt & flag in one pass) -------------------
// (harness-verified rounds 8/9)

__global__ __launch_bounds__(1024) void k_scan_local_dual(const int* __restrict__ cnt,
                                                          const int* __restrict__ flag,
                                                          int* __restrict__ rowp,
                                                          int* __restrict__ fidx,
                                                          int* __restrict__ bsumc,
                                                          int* __restrict__ bsumf, int n) {
  __shared__ int smc[1024];
  __shared__ int smf[1024];
  int tid = threadIdx.x;
  int i = blockIdx.x * 1024 + tid;
  int vc = (i < n) ? cnt[i] : 0;
  int vf = (i < n) ? flag[i] : 0;
  smc[tid] = vc;
  smf[tid] = vf;
  __syncthreads();
  for (int off = 1; off < 1024; off <<= 1) {
    int tc_ = (tid >= off) ? smc[tid - off] : 0;
    int tf_ = (tid >= off) ? smf[tid - off] : 0;
    __syncthreads();
    smc[tid] += tc_;
    smf[tid] += tf_;
    __syncthreads();
  }
  if (i < n) {
    rowp[i] = smc[tid] - vc;  // exclusive (pre-fixup)
    fidx[i] = smf[tid] - vf;
  }
  if (tid == 1023) { bsumc[blockIdx.x] = smc[1023]; bsumf[blockIdx.x] = smf[1023]; }
}

__global__ __launch_bounds__(1024) void k_scan_sums_dual(int* __restrict__ bsumc,
                                                         int* __restrict__ bsumf, int nb) {
  __shared__ int smc[1024];
  __shared__ int smf[1024];
  int tid = threadIdx.x;
  int vc = (tid < nb) ? bsumc[tid] : 0;
  int vf = (tid < nb) ? bsumf[tid] : 0;
  smc[tid] = vc;
  smf[tid] = vf;
  __syncthreads();
  for (int off = 1; off < 1024; off <<= 1) {
    int tc_ = (tid >= off) ? smc[tid - off] : 0;
    int tf_ = (tid >= off) ? smf[tid - off] : 0;
    __syncthreads();
    smc[tid] += tc_;
    smf[tid] += tf_;
    __syncthreads();
  }
  if (tid < nb) { bsumc[tid] = smc[tid] - vc; bsumf[tid] = smf[tid] - vf; }
}

// fixup + cursor + dinv + S1 list emit + s1cnt + rowp[n], fused
__global__ void k_finalize_all(int* __restrict__ rowp, int* __restrict__ fidx,
                               const int* __restrict__ bsumc, const int* __restrict__ bsumf,
                               const int* __restrict__ cnt, const int* __restrict__ flag,
                               int* __restrict__ cursor, float* __restrict__ dinv,
                               int* __restrict__ list, int* __restrict__ s1cnt,
                               int n, int E) {
  int i = blockIdx.x * blockDim.x + threadIdx.x;
  if (i < n) {
    int v = rowp[i] + bsumc[i >> 10];
    rowp[i] = v;
    cursor[i] = v;
    dinv[i] = rsqrtf((float)(cnt[i] + 1));  // +1 self loop
    int f = flag[i];
    int fp = fidx[i] + bsumf[i >> 10];
    if (f) list[fp] = i;
    if (i == n - 1) { s1cnt[0] = fp + f; rowp[n] = E; }
  }
}

__global__ void k_fill(const int* __restrict__ src, const int* __restrict__ dst,
                       int* __restrict__ cursor, int* __restrict__ csr_src, int E) {
  int e = blockIdx.x * blockDim.x + threadIdx.x;
  if (e < E) {
    int pos = atomicAdd(&cursor[dst[e]], 1);
    csr_src[pos] = src[e];
  }
}

// ---------------- fp16 MFMA GEMM, NO-LDS register-direct ----------------
// Round-9 post-mortem: GEMM1 pinned at ~100us across ALL staging schedules AND
// concurrency levels -> the global_load_lds staging path itself caps ~3 TB/s
// aggregate. But this problem has NO LDS-worthy reuse: B (384KB) is L2-resident;
// A is streamed once, its only intra-block reuse (4 waves sharing a 64-row band)
// is served by L2 naturally. So: drop LDS/DMA/barriers ENTIRELY (guide common-
// mistake #7: staging cache-fitting data is pure overhead).
// Block = 256 thr = 4 waves, 64 rows x 256 cols (wave tile 64x64, acc 4x4).
// Each lane loads its MFMA fragments straight from global: A rows i*16+l15 at
// cols kt*32+quad*8 (fp32: 2x float4 + cvt; fp16: half8), B rows wn+j*16+l15
// same cols. 64B-line coalesced across quads. Manual 2-stage pipeline with
// named even/odd frag sets (static indices; no barriers -> compiler schedules
// loads across MFMAs freely). Fragment math identical to the r3-r9 verified
// kernel (LDS tile was exactly A[bm+r][kt*32+c] / Bt[r][kt*32+c]).

template <typename AT>
__device__ __forceinline__ void load_a4(const AT* const (&ap)[4], int k0, half8 (&d)[4]) {
#pragma unroll
  for (int i = 0; i < 4; ++i) {
    if constexpr (std::is_same_v<AT, float>) {
      float4v f0 = *(const float4v*)(ap[i] + k0);
      float4v f1 = *(const float4v*)(ap[i] + k0 + 4);
      half8 h;
      h[0] = (_Float16)f0[0]; h[1] = (_Float16)f0[1];
      h[2] = (_Float16)f0[2]; h[3] = (_Float16)f0[3];
      h[4] = (_Float16)f1[0]; h[5] = (_Float16)f1[1];
      h[6] = (_Float16)f1[2]; h[7] = (_Float16)f1[3];
      d[i] = h;
    } else {
      d[i] = *(const half8*)(ap[i] + k0);
    }
  }
}

__device__ __forceinline__ void load_b4(const _Float16* const (&bp)[4], int k0, half8 (&d)[4]) {
#pragma unroll
  for (int j = 0; j < 4; ++j) d[j] = *(const half8*)(bp[j] + k0);
}

__device__ __forceinline__ void mfma16(const half8 (&a)[4], const half8 (&b)[4],
                                       float4v (&acc)[4][4]) {
#pragma unroll
  for (int i = 0; i < 4; ++i)
#pragma unroll
    for (int j = 0; j < 4; ++j)
      acc[i][j] = __builtin_amdgcn_mfma_f32_16x16x32_f16(a[i], b[j], acc[i][j], 0, 0, 0);
}

template <typename AT, int RELU, int BIAS, int SCALE, int GATHER>
__global__ __launch_bounds__(256) void k_gemm_reg(const AT* __restrict__ A,
                                                  const _Float16* __restrict__ Bt,
                                                  const float* __restrict__ bias,
                                                  const float* __restrict__ rowscale,
                                                  _Float16* __restrict__ out,
                                                  int M, int N, int K,
                                                  const int* __restrict__ ridx,
                                                  const int* __restrict__ rcnt) {
  const int tid = threadIdx.x;
  const int wv = tid >> 6;          // 0..3
  const int ln = tid & 63;
  const int quad = ln >> 4;
  const int l15 = ln & 15;
  const int wn = wv * 64;           // 0,64,128,192
  const int bm = (int)blockIdx.x * 64;

  int Meff = M;
  if constexpr (GATHER) {
    Meff = rcnt[0];
    if (bm >= Meff) return;         // no barriers in kernel; uniform per block
  }

  // per-lane fragment base pointers (row fixed; k advances)
  const AT* ap[4];
#pragma unroll
  for (int i = 0; i < 4; ++i) {
    int li = bm + i * 16 + l15;
    if (li > Meff - 1) li = Meff - 1;      // clamp; epilogue masks r >= Meff
    int grow;
    if constexpr (GATHER) grow = ridx[li]; else grow = li;
    ap[i] = A + (size_t)grow * K + quad * 8;
  }
  const _Float16* bp[4];
#pragma unroll
  for (int j = 0; j < 4; ++j)
    bp[j] = Bt + (size_t)(wn + j * 16 + l15) * K + quad * 8;

  float4v acc[4][4];
#pragma unroll
  for (int i = 0; i < 4; ++i)
#pragma unroll
    for (int j = 0; j < 4; ++j) acc[i][j] = (float4v){0.f, 0.f, 0.f, 0.f};

  const int nk = K >> 5;   // K in {768, 256} -> nk even (24, 8)

  half8 ae[4], ao[4], be[4], bo[4];
  load_a4<AT>(ap, 0, ae);
  load_b4(bp, 0, be);
  for (int kt = 0; kt < nk; kt += 2) {
    load_a4<AT>(ap, (kt + 1) << 5, ao);
    load_b4(bp, (kt + 1) << 5, bo);
    mfma16(ae, be, acc);
    if (kt + 2 < nk) {
      load_a4<AT>(ap, (kt + 2) << 5, ae);
      load_b4(bp, (kt + 2) << 5, be);
    }
    mfma16(ao, bo, acc);
  }

  // epilogue: C/D layout col=lane&15, row=quad*4+reg (verified r3-r9)
#pragma unroll
  for (int j = 0; j < 4; ++j) {
    int c = wn + j * 16 + l15;
    float bv = BIAS ? bias[c] : 0.f;
#pragma unroll
    for (int i = 0; i < 4; ++i) {
      int rbase = bm + i * 16 + quad * 4;
      float4v a = acc[i][j];
#pragma unroll
      for (int reg = 0; reg < 4; ++reg) {
        int r = rbase + reg;
        if (r < Meff) {
          int orow;
          if constexpr (GATHER) orow = ridx[r]; else orow = r;
          float v = a[reg] + bv;
          if (RELU) v = fmaxf(v, 0.f);
          if (SCALE) v *= rowscale[orow];
          out[(size_t)orow * N + c] = (_Float16)v;
        }
      }
    }
  }
}

// ---------------- GCN aggregation (gather, one wave/node, 256 feats) ----------------
// t is PRE-SCALED: t'[i] = t[i]*dinv[i].  out[i] = (t'[i] + sum t'[src]) * dinv[i] + b

template <typename OT>
__global__ __launch_bounds__(256) void k_agg(const _Float16* __restrict__ t,
                                             const int* __restrict__ row_ptr,
                                             const int* __restrict__ csr_src,
                                             const float* __restrict__ dinv,
                                             const float* __restrict__ bias,
                                             OT* __restrict__ out, int n_nodes) {
  int w = (int)((blockIdx.x * 256 + threadIdx.x) >> 6);
  int lane = threadIdx.x & 63;
  if (w >= n_nodes) return;
  float di = dinv[w];
  half4v v = *(const half4v*)(t + (size_t)w * 256 + lane * 4);
  float ax = (float)v[0], ay = (float)v[1], az = (float)v[2], aw = (float)v[3];
  int e0 = row_ptr[w], e1 = row_ptr[w + 1];
  int e = e0;
  for (; e + 4 <= e1; e += 4) {
    int s0 = csr_src[e];
    int s1 = csr_src[e + 1];
    int s2 = csr_src[e + 2];
    int s3 = csr_src[e + 3];
    half4v u0 = *(const half4v*)(t + (size_t)s0 * 256 + lane * 4);
    half4v u1 = *(const half4v*)(t + (size_t)s1 * 256 + lane * 4);
    half4v u2 = *(const half4v*)(t + (size_t)s2 * 256 + lane * 4);
    half4v u3 = *(const half4v*)(t + (size_t)s3 * 256 + lane * 4);
    ax += (float)u0[0] + (float)u1[0] + (float)u2[0] + (float)u3[0];
    ay += (float)u0[1] + (float)u1[1] + (float)u2[1] + (float)u3[1];
    az += (float)u0[2] + (float)u1[2] + (float)u2[2] + (float)u3[2];
    aw += (float)u0[3] + (float)u1[3] + (float)u2[3] + (float)u3[3];
  }
  for (; e < e1; ++e) {
    int s = csr_src[e];
    half4v u = *(const half4v*)(t + (size_t)s * 256 + lane * 4);
    ax += (float)u[0]; ay += (float)u[1]; az += (float)u[2]; aw += (float)u[3];
  }
  const float4 b = ((const float4*)bias)[lane];
  if constexpr (std::is_same_v<OT, float>) {
    float4 o;
    o.x = ax * di + b.x; o.y = ay * di + b.y;
    o.z = az * di + b.z; o.w = aw * di + b.w;
    ((float4*)(out + (size_t)w * 256))[lane] = o;
  } else {
    half4v o;
    o[0] = (_Float16)(ax * di + b.x); o[1] = (_Float16)(ay * di + b.y);
    o[2] = (_Float16)(az * di + b.z); o[3] = (_Float16)(aw * di + b.w);
    *(half4v*)(out + (size_t)w * 256 + lane * 4) = o;
  }
}

// list-driven variant: only nodes in list[0..s1cnt) are aggregated (S1 pruning).
__global__ __launch_bounds__(256) void k_agg_g(const _Float16* __restrict__ t,
                                               const int* __restrict__ row_ptr,
                                               const int* __restrict__ csr_src,
                                               const float* __restrict__ dinv,
                                               const float* __restrict__ bias,
                                               _Float16* __restrict__ out,
                                               const int* __restrict__ list,
                                               const int* __restrict__ s1cnt) {
  int wi = (int)((blockIdx.x * 256 + threadIdx.x) >> 6);
  int lane = threadIdx.x & 63;
  if (wi >= s1cnt[0]) return;      // per-wave uniform; no barriers in kernel
  int w = list[wi];
  float di = dinv[w];
  half4v v = *(const half4v*)(t + (size_t)w * 256 + lane * 4);
  float ax = (float)v[0], ay = (float)v[1], az = (float)v[2], aw = (float)v[3];
  int e0 = row_ptr[w], e1 = row_ptr[w + 1];
  int e = e0;
  for (; e + 4 <= e1; e += 4) {
    int s0 = csr_src[e];
    int s1 = csr_src[e + 1];
    int s2 = csr_src[e + 2];
    int s3 = csr_src[e + 3];
    half4v u0 = *(const half4v*)(t + (size_t)s0 * 256 + lane * 4);
    half4v u1 = *(const half4v*)(t + (size_t)s1 * 256 + lane * 4);
    half4v u2 = *(const half4v*)(t + (size_t)s2 * 256 + lane * 4);
    half4v u3 = *(const half4v*)(t + (size_t)s3 * 256 + lane * 4);
    ax += (float)u0[0] + (float)u1[0] + (float)u2[0] + (float)u3[0];
    ay += (float)u0[1] + (float)u1[1] + (float)u2[1] + (float)u3[1];
    az += (float)u0[2] + (float)u1[2] + (float)u2[2] + (float)u3[2];
    aw += (float)u0[3] + (float)u1[3] + (float)u2[3] + (float)u3[3];
  }
  for (; e < e1; ++e) {
    int s = csr_src[e];
    half4v u = *(const half4v*)(t + (size_t)s * 256 + lane * 4);
    ax += (float)u[0]; ay += (float)u[1]; az += (float)u[2]; aw += (float)u[3];
  }
  const float4 b = ((const float4*)bias)[lane];
  half4v o;
  o[0] = (_Float16)(ax * di + b.x); o[1] = (_Float16)(ay * di + b.y);
  o[2] = (_Float16)(az * di + b.z); o[3] = (_Float16)(aw * di + b.w);
  *(half4v*)(out + (size_t)w * 256 + lane * 4) = o;
}

// ---------------- fused tail: logits = (relu(agg2 @ W2 + b2)) @ Wc + bc ------------
// (harness-verified rounds 7/8/9)

__global__ __launch_bounds__(256) void k_tail(const float* __restrict__ A,
                                              const float* __restrict__ B,
                                              const float* __restrict__ b2,
                                              const float* __restrict__ Wc,
                                              const float* __restrict__ bc,
                                              float* __restrict__ out,
                                              int M, int N, int K) {
  __shared__ float As[16][68];
  __shared__ float Bs[16][136];
  __shared__ float wsm[256];          // Wc: [N][2], N=128
  __shared__ float red[64][16][2];
  const int bm = blockIdx.x * 64;
  const int tid = threadIdx.x;
  const int tr = (tid >> 4) << 2;     // 0..60
  const int tc = (tid & 15) << 3;     // 0..120
  const int lm  = tid >> 2;           // A stage row 0..63
  const int lk  = (tid & 3) << 2;     // A stage k 0,4,8,12
  const int lk2 = tid >> 4;           // B stage k 0..15
  const int ln  = (tid & 15) << 3;    // B stage col 0..120
  wsm[tid] = Wc[tid];
  const bool arow_ok = (bm + lm) < M;
  const float* Aptr = A + (size_t)(bm + lm) * K + lk;
  const float* Bptr = B + (size_t)lk2 * N + ln;
  float acc[4][8] = {};
  for (int k0 = 0; k0 < K; k0 += 16) {
    float4 a4 = make_float4(0.f, 0.f, 0.f, 0.f);
    if (arow_ok) a4 = *(const float4*)(Aptr + k0);
    float4 b4 = *(const float4*)(Bptr + (size_t)k0 * N);
    float4 b5 = *(const float4*)(Bptr + (size_t)k0 * N + 4);
    As[lk + 0][lm] = a4.x;
    As[lk + 1][lm] = a4.y;
    As[lk + 2][lm] = a4.z;
    As[lk + 3][lm] = a4.w;
    *(float4*)&Bs[lk2][ln] = b4;
    *(float4*)&Bs[lk2][ln + 4] = b5;
    __syncthreads();
#pragma unroll
    for (int k = 0; k < 16; ++k) {
      float4 av = *(const float4*)&As[k][tr];
      float a[4] = {av.x, av.y, av.z, av.w};
      float b[8];
      *(float4*)&b[0] = *(const float4*)&Bs[k][tc];
      *(float4*)&b[4] = *(const float4*)&Bs[k][tc + 4];
#pragma unroll
      for (int i = 0; i < 4; ++i)
#pragma unroll
        for (int j = 0; j < 8; ++j) acc[i][j] += a[i] * b[j];
    }
    __syncthreads();
  }
  // relu + b2, then partial logits vs Wc
  float p[4][2] = {};
#pragma unroll
  for (int j = 0; j < 8; ++j) {
    float bb = b2[tc + j];
    float w0 = wsm[(tc + j) * 2 + 0];
    float w1 = wsm[(tc + j) * 2 + 1];
#pragma unroll
    for (int i = 0; i < 4; ++i) {
      float v = fmaxf(acc[i][j] + bb, 0.f);
      p[i][0] += v * w0;
      p[i][1] += v * w1;
    }
  }
#pragma unroll
  for (int i = 0; i < 4; ++i) {
    red[tr + i][tid & 15][0] = p[i][0];
    red[tr + i][tid & 15][1] = p[i][1];
  }
  __syncthreads();
  if (tid < 128) {
    int row = tid >> 1, kk = tid & 1;
    float s = 0.f;
#pragma unroll
    for (int t = 0; t < 16; ++t) s += red[row][t][kk];
    int r = bm + row;
    if (r < M) out[2 * r + kk] = s + bc[kk];
  }
}

// ---------------- launch ----------------

extern "C" void kernel_launch(void* const* d_in, const int* in_sizes, int n_in,
                              void* d_out, int out_size, void* d_ws, size_t ws_size,
                              hipStream_t stream) {
  const float* x   = (const float*)d_in[0];
  const int*   ei  = (const int*)d_in[1];
  const float* W1  = (const float*)d_in[2];
  const float* b1  = (const float*)d_in[3];
  const float* Wg1 = (const float*)d_in[4];
  const float* bg1 = (const float*)d_in[5];
  const float* Wg2 = (const float*)d_in[6];
  const float* bg2 = (const float*)d_in[7];
  const float* W2  = (const float*)d_in[8];
  const float* b2  = (const float*)d_in[9];
  const float* Wc  = (const float*)d_in[10];
  const float* bc  = (const float*)d_in[11];
  float* out = (float*)d_out;

  const int hid     = in_sizes[3];            // 256
  const int in_dim  = in_sizes[2] / hid;      // 768
  const int out_dim = in_sizes[9];            // 128
  const int N       = in_sizes[0] / in_dim;   // 50000
  const int E       = in_sizes[1] / 2;        // 800000
  const int Batch   = out_size / 2;           // 1024

  const int* srcI = ei;
  const int* dstI = ei + E;

  char* ws = (char*)d_ws;
  size_t off = 0;
  auto alloc = [&](size_t bytes) -> void* {
    void* p = ws + off;
    off = (off + bytes + 255) & ~(size_t)255;
    return p;
  };
  _Float16* h0h  = (_Float16*)alloc((size_t)N * hid * 2);
  _Float16* t1h  = (_Float16*)alloc((size_t)N * hid * 2);   // pre-scaled by dinv
  _Float16* h1h  = (_Float16*)alloc((size_t)N * hid * 2);   // only S1 rows valid
  _Float16* t2h  = (_Float16*)alloc((size_t)N * hid * 2);   // only S1 rows valid
  _Float16* W1t  = (_Float16*)alloc((size_t)in_dim * hid * 2);
  _Float16* Wg1t = (_Float16*)alloc((size_t)hid * hid * 2);
  _Float16* Wg2t = (_Float16*)alloc((size_t)hid * hid * 2);
  float* agg2    = (float*)alloc((size_t)Batch * hid * 4);
  float* dinv    = (float*)alloc((size_t)N * 4);
  int*   cnt     = (int*)alloc((size_t)N * 4);
  int*   rowp    = (int*)alloc((size_t)(N + 1) * 4);
  int*   fidx    = (int*)alloc((size_t)N * 4);
  int*   bsumc   = (int*)alloc((size_t)1024 * 4);
  int*   bsumf   = (int*)alloc((size_t)1024 * 4);
  int*   cursor  = (int*)alloc((size_t)N * 4);
  int*   csrs    = (int*)alloc((size_t)E * 4);
  int*   flag    = (int*)alloc((size_t)N * 4);
  int*   list    = (int*)alloc((size_t)N * 4);
  int*   s1cnt   = (int*)alloc((size_t)64);
  (void)ws_size; (void)n_in;

  dim3 blk(256);
  const int nb = (N + 1023) / 1024;

  // 1) zero + weight convert (fused)
  {
    int total = N + in_dim * hid + 2 * hid * hid;
    k_prep<<<(total + 255) / 256, blk, 0, stream>>>(cnt, flag, W1, Wg1, Wg2,
                                                    W1t, Wg1t, Wg2t, N, in_dim, hid);
  }
  // 2) count + S1 mark (fused E pass)
  k_countmark<<<(E + 255) / 256, blk, 0, stream>>>(srcI, dstI, cnt, flag, E, Batch);
  // 3-5) parallel dual scan + finalize/emit
  k_scan_local_dual<<<nb, 1024, 0, stream>>>(cnt, flag, rowp, fidx, bsumc, bsumf, N);
  k_scan_sums_dual<<<1, 1024, 0, stream>>>(bsumc, bsumf, nb);
  k_finalize_all<<<(N + 255) / 256, blk, 0, stream>>>(rowp, fidx, bsumc, bsumf, cnt, flag,
                                                      cursor, dinv, list, s1cnt, N, E);
  // 6) CSR fill
  k_fill<<<(E + 255) / 256, blk, 0, stream>>>(srcI, dstI, cursor, csrs, E);

  const int ng = (N + 63) / 64;   // 782 blocks, 64 rows x full-N cols each
  // 7) h0 = relu(x @ W1 + b1)
  k_gemm_reg<float, 1, 1, 0, 0><<<dim3(ng), blk, 0, stream>>>(x, W1t, b1, nullptr, h0h, N, hid, in_dim, nullptr, nullptr);
  // 8) t1' = (h0 @ Wg1) * dinv[row]   (all nodes)
  k_gemm_reg<_Float16, 0, 0, 1, 0><<<dim3(ng), blk, 0, stream>>>(h0h, Wg1t, nullptr, dinv, t1h, N, hid, hid, nullptr, nullptr);
  // 9) h1 = (t1'[i] + sum t1'[src]) * dinv[i] + bg1   -- S1 nodes only
  k_agg_g<<<(N + 3) / 4, blk, 0, stream>>>(t1h, rowp, csrs, dinv, bg1, h1h, list, s1cnt);
  // 10) t2' = (h1 @ Wg2) * dinv[row]   -- gather over S1 rows
  k_gemm_reg<_Float16, 0, 0, 1, 1><<<dim3(ng), blk, 0, stream>>>(h1h, Wg2t, nullptr, dinv, t2h, N, hid, hid, list, s1cnt);
  // 11) conv2 aggregation for rows [0, Batch) (fp32 out)
  k_agg<float><<<(Batch + 3) / 4, blk, 0, stream>>>(t2h, rowp, csrs, dinv, bg2, agg2, Batch);
  // 12) logits = relu(agg2 @ W2 + b2) @ Wc + bc   (fused tail)
  k_tail<<<(Batch + 63) / 64, blk, 0, stream>>>(agg2, W2, b2, Wc, bc, out, Batch, out_dim, hid);
}